// Round 6
// baseline (1091.463 us; speedup 1.0000x reference)
//
#include <hip/hip_runtime.h>
#include <hip/hip_cooperative_groups.h>

namespace cg = cooperative_groups;

#define N_NODES 50000
#define N_EDGES 600000
#define HDIM 128
#define KEIG 32
#define AGG4 512   // 4*H aggregate block
#define CAP 96     // per-node edge slot capacity (mean degree 12; P(deg>=96) ~ 1e-45)

#define W1SZ 147456   // 36*8*64*8  (W_post swizzle elements)
#define W2SZ 16384    // 4*8*64*8   (W_last half swizzle elements)

typedef short s8v __attribute__((ext_vector_type(8)));
typedef __bf16 bf8v __attribute__((ext_vector_type(8)));
typedef float f4v __attribute__((ext_vector_type(4)));

__device__ __forceinline__ unsigned short f2bf(float f) {
    unsigned u = __float_as_uint(f);
    u += 0x7fff + ((u >> 16) & 1);   // round to nearest even
    return (unsigned short)(u >> 16);
}
__device__ __forceinline__ float bf2f(unsigned short h) {
    return __uint_as_float(((unsigned)h) << 16);
}
__device__ __forceinline__ unsigned pack2(float a, float b) {
    return (unsigned)f2bf(a) | ((unsigned)f2bf(b) << 16);
}
__device__ __forceinline__ bf8v as_bf(s8v v) { return __builtin_bit_cast(bf8v, v); }

// ============================ cooperative mega-kernel ========================
// Phases (grid.sync between each):
//   Z: zero coeff+cnt
//   F: W pre-swizzle  U  coeff projection  U  edge bucketing   (input-only deps)
//   D: spectral diffusion -> xb
//   A: per-node aggregation -> aggs
//   G: fused dual-GEMM + epilogues -> out
// Phase bodies are identical to the round-5 proven kernels, wrapped in
// grid-stride loops so any co-resident grid size works.
__global__ __launch_bounds__(256, 4) void k_mega(
    const float* __restrict__ Wp, const float* __restrict__ Wl,
    unsigned short* __restrict__ Wswz, unsigned short* __restrict__ WlA,
    unsigned short* __restrict__ WlB,
    const float* __restrict__ node_fts, const float* __restrict__ degv,
    const float* __restrict__ eig, float* __restrict__ coeff,
    const int* __restrict__ ei, const float* __restrict__ F,
    int* __restrict__ cnt, int2* __restrict__ ssrcF,
    unsigned short* __restrict__ xb, unsigned short* __restrict__ aggs,
    const float* __restrict__ lam, const float* __restrict__ dt,
    const float* __restrict__ Fdig, const float* __restrict__ b_post,
    const float* __restrict__ b_last, const float* __restrict__ norm_n,
    float* __restrict__ out) {
    cg::grid_group grid = cg::this_grid();
    __shared__ __align__(16) float c2s[KEIG * HDIM];          // 16 KB (diffuse)
    unsigned short* Hs = (unsigned short*)c2s;                 // 5 KB alias (gemm)

    int b = blockIdx.x, t = threadIdx.x;
    int gsize = gridDim.x * 256;
    int gtid = b * 256 + t;

    // ---- Z: zero coeff (4096 f32) + cnt (50000 i32) ----
    for (int i = gtid; i < KEIG * HDIM; i += gsize) coeff[i] = 0.f;
    for (int i = gtid; i < N_NODES; i += gsize) cnt[i] = 0;
    grid.sync();

    // ---- F1: W_post/W_last -> MFMA B-fragment order [step][ntile][lane][j] ----
    for (int i = gtid; i < W1SZ + W2SZ; i += gsize) {
        if (i < W1SZ) {
            int j = i & 7, lane = (i >> 3) & 63, tn = (i >> 9) & 7, s = i >> 12;
            int k = s * 32 + (lane >> 4) * 8 + j;
            int c = tn * 16 + (lane & 15);
            Wswz[i] = f2bf(Wp[k * HDIM + c]);
        } else {
            int t2 = i - W1SZ;
            int j = t2 & 7, lane = (t2 >> 3) & 63, tn = (t2 >> 9) & 7, s = t2 >> 12;
            int k = s * 32 + (lane >> 4) * 8 + j;
            int c = tn * 16 + (lane & 15);
            WlA[t2] = f2bf(Wl[k * HDIM + c]);
            WlB[t2] = f2bf(Wl[(128 + k) * HDIM + c]);
        }
    }
    // ---- F2: coeff[k,h] += sum_n eig[n,k]*deg[n]*x[n,h]; 64 nodes per bb ----
    {
        int half = t >> 7, h = t & 127;
        for (int bb = b; bb < 782; bb += gridDim.x) {
            int base = bb * 64 + half * 32;
            if (base < N_NODES) {
                int lim = N_NODES - base; if (lim > 32) lim = 32;
                float acc[KEIG];
#pragma unroll
                for (int k = 0; k < KEIG; k++) acc[k] = 0.f;
                for (int r = 0; r < lim; r++) {
                    int n = base + r;
                    float v = degv[n] * node_fts[n * HDIM + h];
                    const float4* e4 = (const float4*)(eig + n * KEIG);
#pragma unroll
                    for (int q = 0; q < 8; q++) {
                        float4 e = e4[q];
                        acc[q * 4 + 0] += e.x * v;
                        acc[q * 4 + 1] += e.y * v;
                        acc[q * 4 + 2] += e.z * v;
                        acc[q * 4 + 3] += e.w * v;
                    }
                }
#pragma unroll
                for (int k = 0; k < KEIG; k++) atomicAdd(&coeff[k * HDIM + h], acc[k]);
            }
        }
    }
    // ---- F3: bucket edges into fixed-capacity per-node slots ----
    for (int e = gtid; e < N_EDGES; e += gsize) {
        int d = ei[N_EDGES + e];
        int p = atomicAdd(&cnt[d], 1);
        if (p < CAP) ssrcF[(size_t)d * CAP + p] = make_int2(ei[e], __float_as_int(F[e]));
    }
    grid.sync();

    // ---- D: x[n,h] = sum_k eig[n,k]*coeff[k,h]*exp(-lam_k*softplus(t_h)) ----
    {
        int h = t & 127, sub = t >> 7;
        float tt = log1pf(expf(dt[h]));
#pragma unroll
        for (int j = sub * 16; j < sub * 16 + 16; j++)
            c2s[j * HDIM + h] = coeff[j * HDIM + h] * expf(-lam[j] * tt);
        __syncthreads();
        for (int bb = b; bb < 391; bb += gridDim.x) {
            int base = bb * 128 + sub * 64;
            for (int r = 0; r < 64; r++) {
                int n = base + r;
                if (n >= N_NODES) break;
                const float4* e4 = (const float4*)(eig + n * KEIG);
                float s = 0.f;
#pragma unroll
                for (int q = 0; q < 8; q++) {
                    float4 e = e4[q];
                    s += e.x * c2s[(q * 4 + 0) * HDIM + h] + e.y * c2s[(q * 4 + 1) * HDIM + h]
                       + e.z * c2s[(q * 4 + 2) * HDIM + h] + e.w * c2s[(q * 4 + 3) * HDIM + h];
                }
                xb[(size_t)n * HDIM + h] = f2bf(s);
            }
        }
    }
    grid.sync();

    // ---- A: per-node aggregation -> aggs[N,512]; 4 nodes per group ----
    for (int g = b; g < 12500; g += gridDim.x) {
        int n = g * 4 + (t >> 6);
        if (n < N_NODES) {
            int tl = t & 63;  // channels 2tl, 2tl+1
            int end = cnt[n]; if (end > CAP) end = CAP;
            const int2* es = ssrcF + (size_t)n * CAP;
            const unsigned* fx = (const unsigned*)xb;  // row pitch = 64 uints
            float s0 = 0.f, s1 = 0.f, w0 = 0.f, w1 = 0.f, f0 = 0.f, f1 = 0.f;
            float m0 = -3.4e38f, m1 = -3.4e38f, wS = 0.f;
            int e = 0;
            for (; e + 3 < end; e += 4) {
                int2 ea = es[e], eb = es[e + 1], ec = es[e + 2], ed = es[e + 3];
                float Fa = __int_as_float(ea.y), Fb = __int_as_float(eb.y);
                float Fc = __int_as_float(ec.y), Fd = __int_as_float(ed.y);
                unsigned va = fx[(size_t)ea.x * 64 + tl];
                unsigned vb = fx[(size_t)eb.x * 64 + tl];
                unsigned vc = fx[(size_t)ec.x * 64 + tl];
                unsigned vd = fx[(size_t)ed.x * 64 + tl];
                float wa = fabsf(Fa), wb = fabsf(Fb), wc = fabsf(Fc), wd = fabsf(Fd);
                wS += wa + wb + wc + wd;
                float a0 = bf2f(va & 0xffff), a1 = bf2f(va >> 16);
                float b0 = bf2f(vb & 0xffff), b1 = bf2f(vb >> 16);
                float c0 = bf2f(vc & 0xffff), c1 = bf2f(vc >> 16);
                float d0 = bf2f(vd & 0xffff), d1 = bf2f(vd >> 16);
                s0 += a0 + b0 + c0 + d0;  s1 += a1 + b1 + c1 + d1;
                m0 = fmaxf(fmaxf(fmaxf(m0, a0), fmaxf(b0, c0)), d0);
                m1 = fmaxf(fmaxf(fmaxf(m1, a1), fmaxf(b1, c1)), d1);
                w0 += wa * a0 + wb * b0 + wc * c0 + wd * d0;
                w1 += wa * a1 + wb * b1 + wc * c1 + wd * d1;
                f0 += Fa * a0 + Fb * b0 + Fc * c0 + Fd * d0;
                f1 += Fa * a1 + Fb * b1 + Fc * c1 + Fd * d1;
            }
            for (; e < end; e++) {
                int2 ea = es[e];
                float Fa = __int_as_float(ea.y), wa = fabsf(Fa);
                unsigned va = fx[(size_t)ea.x * 64 + tl];
                float a0 = bf2f(va & 0xffff), a1 = bf2f(va >> 16);
                s0 += a0; s1 += a1;
                m0 = fmaxf(m0, a0); m1 = fmaxf(m1, a1);
                w0 += wa * a0; w1 += wa * a1;
                f0 += Fa * a0; f1 += Fa * a1;
                wS += wa;
            }
            float dv = degv[n];
            float inv = 1.f / dv;
            float me0 = s0 * inv, me1 = s1 * inv;
            float mx0 = (end > 0) ? m0 : 0.f, mx1 = (end > 0) ? m1 : 0.f;
            float wi = 1.f / (wS + 1e-8f);
            float da0 = w0 * wi, da1 = w1 * wi;
            unsigned vx = fx[(size_t)n * 64 + tl];
            float Fg = Fdig[n];
            float dd0 = f0 - Fg * bf2f(vx & 0xffff);
            float dd1 = f1 - Fg * bf2f(vx >> 16);
            unsigned* fr = (unsigned*)aggs + (size_t)n * 256 + tl;
            fr[0]   = pack2(me0, me1);
            fr[64]  = pack2(mx0, mx1);
            fr[128] = pack2(da0, da1);
            fr[192] = pack2(dd0, dd1);
        }
    }
    grid.sync();

    // ---- G: fused dual-GEMM (LDS-free A-path, round-4/5 proven) ----
    {
        int wave = t >> 6, lane = t & 63;
        int m16 = lane & 15, quad = lane >> 4;
        for (int gb = b; gb < 782; gb += gridDim.x) {
            int r0 = gb * 64;
            int arow = r0 + wave * 16 + m16;
            if (arow > N_NODES - 1) arow = N_NODES - 1;   // dup last row; masked
            const unsigned short* aX = xb + (size_t)arow * HDIM + quad * 8;
            const unsigned short* aG = aggs + (size_t)arow * AGG4 + quad * 8;

            f4v accU[8], accV[8];
#pragma unroll
            for (int i = 0; i < 8; i++) { accU[i] = (f4v)(0.f); accV[i] = (f4v)(0.f); }

            // x block: steps 0..3 (accU only)
#pragma unroll
            for (int s = 0; s < 4; s++) {
                s8v a = *(const s8v*)(aX + s * 32);
                const s8v* bu = (const s8v*)Wswz + (size_t)(s * 8) * 64 + lane;
#pragma unroll
                for (int nt = 0; nt < 8; nt++) {
                    s8v bb = bu[nt * 64];
                    accU[nt] = __builtin_amdgcn_mfma_f32_16x16x32_bf16(as_bf(a), as_bf(bb), accU[nt], 0, 0, 0);
                }
            }
            // agg block: 16 steps, dual-B
            for (int s2 = 0; s2 < 16; s2++) {
                s8v a = *(const s8v*)(aG + s2 * 32);
                const s8v* bu = (const s8v*)Wswz + (size_t)((s2 + 4) * 8) * 64 + lane;
                const s8v* bv = (const s8v*)Wswz + (size_t)((s2 + 20) * 8) * 64 + lane;
#pragma unroll
                for (int nt = 0; nt < 8; nt++) {
                    s8v bb = bu[nt * 64];
                    accU[nt] = __builtin_amdgcn_mfma_f32_16x16x32_bf16(as_bf(a), as_bf(bb), accU[nt], 0, 0, 0);
                    s8v b2 = bv[nt * 64];
                    accV[nt] = __builtin_amdgcn_mfma_f32_16x16x32_bf16(as_bf(a), as_bf(b2), accV[nt], 0, 0, 0);
                }
            }

            // epilogue1: h = relu(accU + amp*accV + b_post) * norm_n
            int browbase = r0 + wave * 16 + quad * 4;
            float nrm[4], amp[4];
#pragma unroll
            for (int r = 0; r < 4; r++) {
                int gr = browbase + r;
                if (gr > N_NODES - 1) gr = N_NODES - 1;
                nrm[r] = norm_n[gr];
                amp[r] = log1pf(degv[gr]) / 2.5649493574615367f;  // log(13)
            }
#pragma unroll
            for (int nt = 0; nt < 8; nt++) {
                float bb = b_post[nt * 16 + m16];
#pragma unroll
                for (int r = 0; r < 4; r++) {
                    float v = accU[nt][r] + amp[r] * accV[nt][r] + bb;
                    v = v > 0.f ? v : 0.f;
                    accU[nt][r] = v * nrm[r];
                }
            }

            // GEMM2: out = h@WlB + x@WlA ; h transposed 32 cols/step (wave-local)
            f4v acc2[8];
#pragma unroll
            for (int i = 0; i < 8; i++) acc2[i] = (f4v)(0.f);
#pragma unroll
            for (int s = 0; s < 4; s++) {
#pragma unroll
                for (int half = 0; half < 2; half++) {
                    int nt = s * 2 + half;
#pragma unroll
                    for (int r = 0; r < 4; r++)
                        Hs[(wave * 16 + quad * 4 + r) * 40 + half * 16 + m16] = f2bf(accU[nt][r]);
                }
                s8v a = *(const s8v*)(&Hs[(wave * 16 + m16) * 40 + quad * 8]);
                s8v xa = *(const s8v*)(aX + s * 32);
                const s8v* bB = (const s8v*)WlB + (size_t)(s * 8) * 64 + lane;
                const s8v* bA = (const s8v*)WlA + (size_t)(s * 8) * 64 + lane;
#pragma unroll
                for (int nt = 0; nt < 8; nt++) {
                    s8v bb = bB[nt * 64];
                    acc2[nt] = __builtin_amdgcn_mfma_f32_16x16x32_bf16(as_bf(a), as_bf(bb), acc2[nt], 0, 0, 0);
                    s8v b2 = bA[nt * 64];
                    acc2[nt] = __builtin_amdgcn_mfma_f32_16x16x32_bf16(as_bf(xa), as_bf(b2), acc2[nt], 0, 0, 0);
                }
            }

            // epilogue2: out = acc2 + b_last + node_fts
#pragma unroll
            for (int nt = 0; nt < 8; nt++) {
                int col = nt * 16 + m16;
                float bl = b_last[col];
#pragma unroll
                for (int r = 0; r < 4; r++) {
                    int gr = browbase + r;
                    if (gr < N_NODES) {
                        out[(size_t)gr * HDIM + col] = acc2[nt][r] + bl + node_fts[(size_t)gr * HDIM + col];
                    }
                }
            }
        }
    }
}

extern "C" void kernel_launch(void* const* d_in, const int* in_sizes, int n_in,
                              void* d_out, int out_size, void* d_ws, size_t ws_size,
                              hipStream_t stream) {
    const float* node_fts = (const float*)d_in[0];
    const int*   eidx     = (const int*)d_in[2];
    const float* Fnorm    = (const float*)d_in[3];
    const float* Fdig     = (const float*)d_in[4];
    const float* degv     = (const float*)d_in[5];
    const float* lam      = (const float*)d_in[8];
    const float* eig      = (const float*)d_in[9];
    const float* norm_n   = (const float*)d_in[11];
    const float* dtimes   = (const float*)d_in[13];
    const float* Wp       = (const float*)d_in[14];
    const float* bp       = (const float*)d_in[15];
    const float* Wl       = (const float*)d_in[16];
    const float* bl       = (const float*)d_in[17];
    float* out = (float*)d_out;

    char* w = (char*)d_ws;
    size_t off = 0;
    auto carve = [&](size_t bytes) -> char* {
        char* p = w + off;
        off = (off + bytes + 255) & ~(size_t)255;
        return p;
    };
    unsigned short* xbuf  = (unsigned short*)carve((size_t)N_NODES * HDIM * 2);
    unsigned short* aggs  = (unsigned short*)carve((size_t)N_NODES * AGG4 * 2);
    unsigned short* Wswz  = (unsigned short*)carve((size_t)W1SZ * 2);
    unsigned short* WlA   = (unsigned short*)carve((size_t)W2SZ * 2);
    unsigned short* WlB   = (unsigned short*)carve((size_t)W2SZ * 2);
    float* coeff  = (float*)carve(KEIG * HDIM * 4);
    int* cnt      = (int*)carve((size_t)N_NODES * 4);
    int2* ssrcF   = (int2*)carve((size_t)N_NODES * CAP * 8);

    // co-resident grid size (launch_bounds(256,4) + 16KB LDS -> 4 blocks/CU)
    int perCU = 0;
    hipOccupancyMaxActiveBlocksPerMultiprocessor(&perCU, k_mega, 256, 0);
    if (perCU < 1) perCU = 1;
    int grid = perCU * 256;
    if (grid > 1024) grid = 1024;

    void* args[] = {
        (void*)&Wp, (void*)&Wl, (void*)&Wswz, (void*)&WlA, (void*)&WlB,
        (void*)&node_fts, (void*)&degv, (void*)&eig, (void*)&coeff,
        (void*)&eidx, (void*)&Fnorm, (void*)&cnt, (void*)&ssrcF,
        (void*)&xbuf, (void*)&aggs,
        (void*)&lam, (void*)&dtimes,
        (void*)&Fdig, (void*)&bp, (void*)&bl, (void*)&norm_n,
        (void*)&out
    };
    hipLaunchCooperativeKernel(k_mega, dim3(grid), dim3(256), args, 0, stream);
}